// Round 3
// baseline (295.079 us; speedup 1.0000x reference)
//
#include <hip/hip_runtime.h>
#include <hip/hip_bf16.h>

#define B_  8192
#define D_  784
#define H_  2048
#define O_  1024
#define RH_ 128
#define P_  64
#define KP  224   // 196 padded to 7*32

typedef __attribute__((ext_vector_type(8))) short short8;
typedef __attribute__((ext_vector_type(4))) float f32x4;

__device__ inline float bf2f(unsigned short u) {
  union { unsigned int i; float f; } v; v.i = ((unsigned int)u) << 16; return v.f;
}
__device__ inline unsigned short f2bf(float f) {
  __hip_bfloat16 h = __float2bfloat16(f);
  return *reinterpret_cast<unsigned short*>(&h);
}
// Abramowitz-Stegun 7.1.26, max abs err ~1.5e-7 (exact-gelu grade)
__device__ inline float erf_fast(float x) {
  float ax = fabsf(x);
  float t = 1.0f / (1.0f + 0.3275911f * ax);
  float p = ((((1.061405429f * t - 1.453152027f) * t + 1.421413741f) * t
              - 0.284496736f) * t + 0.254829592f) * t;
  float y = 1.0f - p * __expf(-ax * ax);
  return x < 0.f ? -y : y;
}
__device__ inline float gelu_exact(float v) {
  return 0.5f * v * (1.0f + erf_fast(v * 0.70710678118654752f));
}

__device__ inline void gload_lds16(const void* g, void* l) {
  __builtin_amdgcn_global_load_lds((const __attribute__((address_space(1))) void*)g,
                                   (__attribute__((address_space(3))) void*)l, 16, 0, 0);
}

// ---- prep: gather/pad/convert x_reg, W1g; convert W2 to bf16 ----
__global__ void k_prep(const float* __restrict__ x, const float* __restrict__ W1,
                       const float* __restrict__ W2, const int* __restrict__ ig,
                       unsigned short* __restrict__ xreg, unsigned short* __restrict__ w1g,
                       unsigned short* __restrict__ w2b) {
  const size_t N1 = (size_t)4 * B_ * KP;
  const size_t N2 = (size_t)4 * H_ * KP;
  const size_t N3 = (size_t)O_ * H_;
  const size_t TOT = N1 + N2 + N3;
  for (size_t idx = (size_t)blockIdx.x * blockDim.x + threadIdx.x; idx < TOT;
       idx += (size_t)gridDim.x * blockDim.x) {
    if (idx < N1) {
      int n = (int)(idx % KP); size_t r = idx / KP;
      int b = (int)(r % B_); int i = (int)(r / B_);
      float v = (n < 196) ? x[(size_t)b * D_ + ig[i * 196 + n]] : 0.f;
      xreg[idx] = f2bf(v);
    } else if (idx < N1 + N2) {
      size_t q = idx - N1;
      int n = (int)(q % KP); size_t r = q / KP;
      int h = (int)(r % H_); int i = (int)(r / H_);
      float v = (n < 196) ? W1[(size_t)h * D_ + ig[i * 196 + n]] : 0.f;
      w1g[q] = f2bf(v);
    } else {
      size_t q = idx - N1 - N2;
      w2b[q] = f2bf(W2[q]);
    }
  }
}

// ---- router stage 1: h_r = relu(x @ Wr1^T + br1), fp32 register-blocked GEMM ----
__global__ __launch_bounds__(256) void k_r1(const float* __restrict__ x,
    const float* __restrict__ Wr1, const float* __restrict__ br1,
    float* __restrict__ hr) {
  __shared__ float As[64][33];
  __shared__ float Bs[64][33];
  const int b0 = blockIdx.x * 64;
  const int h0 = blockIdx.y * 64;
  const int t = threadIdx.x;
  const int srow = t >> 2;
  const int scol = (t & 3) * 8;
  const int ty = t >> 4, tx = t & 15;
  float acc[4][4];
#pragma unroll
  for (int i = 0; i < 4; ++i)
#pragma unroll
    for (int j = 0; j < 4; ++j) acc[i][j] = 0.f;
  const float* gA = x   + (size_t)(b0 + srow) * D_;
  const float* gB = Wr1 + (size_t)(h0 + srow) * D_;
  for (int k0 = 0; k0 < D_; k0 += 32) {
    float4 a0 = (k0 + scol     < D_) ? *(const float4*)(gA + k0 + scol)     : float4{0,0,0,0};
    float4 a1 = (k0 + scol + 4 < D_) ? *(const float4*)(gA + k0 + scol + 4) : float4{0,0,0,0};
    float4 w0 = (k0 + scol     < D_) ? *(const float4*)(gB + k0 + scol)     : float4{0,0,0,0};
    float4 w1 = (k0 + scol + 4 < D_) ? *(const float4*)(gB + k0 + scol + 4) : float4{0,0,0,0};
    __syncthreads();
    *(float4*)&As[srow][scol]     = a0;
    *(float4*)&As[srow][scol + 4] = a1;
    *(float4*)&Bs[srow][scol]     = w0;
    *(float4*)&Bs[srow][scol + 4] = w1;
    __syncthreads();
#pragma unroll
    for (int kk = 0; kk < 8; ++kk) {
      float4 a4[4], b4[4];
#pragma unroll
      for (int i = 0; i < 4; ++i) a4[i] = *(const float4*)&As[ty * 4 + i][kk * 4];
#pragma unroll
      for (int j = 0; j < 4; ++j) b4[j] = *(const float4*)&Bs[tx * 4 + j][kk * 4];
#pragma unroll
      for (int i = 0; i < 4; ++i)
#pragma unroll
        for (int j = 0; j < 4; ++j)
          acc[i][j] += a4[i].x * b4[j].x + a4[i].y * b4[j].y +
                       a4[i].z * b4[j].z + a4[i].w * b4[j].w;
    }
  }
#pragma unroll
  for (int j = 0; j < 4; ++j) {
    const int h = h0 + tx * 4 + j;
    const float bias = br1[h];
#pragma unroll
    for (int i = 0; i < 4; ++i)
      hr[(size_t)(b0 + ty * 4 + i) * RH_ + h] = fmaxf(acc[i][j] + bias, 0.f);
  }
}

// ---- router stage 2: scores -> softmax -> top-8 -> weights. One wave per sample. ----
#define R2S 32
__global__ __launch_bounds__(256) void k_r2(const float* __restrict__ hr,
    const float* __restrict__ Wr2, const float* __restrict__ br2,
    float* __restrict__ wts, float* __restrict__ wsum) {
  __shared__ float Ws[64][130];
  __shared__ float hs[R2S][128];
  const int s0 = blockIdx.x * R2S;
  const int t = threadIdx.x;
  for (int idx = t; idx < 2048; idx += 256) {
    int r = idx >> 5, c = (idx & 31) * 4;
    *(float4*)&Ws[r][c] = *(const float4*)(Wr2 + (size_t)r * RH_ + c);
  }
  for (int idx = t; idx < R2S * 32; idx += 256) {
    int r = idx >> 5, c = (idx & 31) * 4;
    *(float4*)&hs[r][c] = *(const float4*)(hr + (size_t)(s0 + r) * RH_ + c);
  }
  __syncthreads();
  const int w = t >> 6, p = t & 63;
  const float wb2 = br2[p];
  for (int si = 0; si < R2S / 4; ++si) {
    const int sl = w * (R2S / 4) + si;
    float sc = wb2;
#pragma unroll
    for (int kk = 0; kk < 32; ++kk) {
      float4 h4 = *(const float4*)&hs[sl][kk * 4];
      float4 w4 = *(const float4*)&Ws[p][kk * 4];
      sc += h4.x * w4.x + h4.y * w4.y + h4.z * w4.z + h4.w * w4.w;
    }
    float m = sc;
#pragma unroll
    for (int o = 32; o; o >>= 1) m = fmaxf(m, __shfl_xor(m, o));
    float e = __expf(sc - m);
    float Z = e;
#pragma unroll
    for (int o = 32; o; o >>= 1) Z += __shfl_xor(Z, o);
    bool sel = false;
    float ssum = 0.f;
    for (int it = 0; it < 8; ++it) {
      float v = sel ? -1.f : e;
      float vm = v;
#pragma unroll
      for (int o = 32; o; o >>= 1) vm = fmaxf(vm, __shfl_xor(vm, o));
      unsigned long long mask = __ballot(!sel && v == vm);
      int first = __ffsll((long long)mask) - 1;
      if (p == first) sel = true;
      ssum += vm;
    }
    const float dn = 1.0f / (ssum + 1e-8f * Z);
    const float wv = sel ? e * dn : 0.f;
    wts[(size_t)(s0 + sl) * 64 + p] = wv;
    float part = wv;
#pragma unroll
    for (int o = 4; o < 64; o <<= 1) part += __shfl_xor(part, o);
    if (p < 4) wsum[(size_t)(s0 + sl) * 4 + p] = part;
  }
}

// ---- fused layer1 + combine: G[k][b][n] = sum_i gelu(xreg_i@w1g_i^T + b1) * wts4[b,i,j(n),k]
// block tile M=128 (b), N=64 (h); 4 waves 2x2 -> wave tile 64x32; i sequential.
// LDS: A 128x32 bf16 (8KB, swizzled) + B 64x32 bf16 (4KB, swizzled) = 12KB.
__global__ __launch_bounds__(256, 2) void k_l1c(const unsigned short* __restrict__ xreg,
    const unsigned short* __restrict__ w1g, const float* __restrict__ b1,
    const float* __restrict__ wts, unsigned short* __restrict__ G) {
  __shared__ __align__(128) char lds[12288];
  const int mt = blockIdx.x, nt = blockIdx.y;
  const int t = threadIdx.x;
  const int w = t >> 6, l = t & 63;
  const int wr = (w >> 1) * 64, wc = (w & 1) * 32;
  const int lr = l & 15;
  // T2 swizzle: LDS slot (row, s) holds source slot s ^ ((row>>1)&3); dest stays linear
  const int swr = (lr >> 1) & 3;
  const int arow = (wr + lr) * 64 + (((l >> 4) ^ swr) * 16);
  const int brow = 8192 + (wc + lr) * 64 + (((l >> 4) ^ swr) * 16);
  const int s_orig = (t & 3) ^ ((t >> 3) & 3);
  const size_t srcOff = (size_t)(t >> 2) * KP + s_orig * 8;
  char* ldsTA = lds + t * 16;
  char* ldsTB = lds + 8192 + t * 16;
  const int h0 = nt * 64;
  const int j = h0 >> 9;
  const float bias0 = b1[h0 + wc + lr];
  const float bias1 = b1[h0 + wc + 16 + lr];
  const int mbase = mt * 128 + wr + (l >> 4) * 4;
  f32x4 out[4][4][2];   // [k][fm][fn]
#pragma unroll
  for (int k = 0; k < 4; ++k)
#pragma unroll
    for (int fm = 0; fm < 4; ++fm)
#pragma unroll
      for (int fn = 0; fn < 2; ++fn) out[k][fm][fn] = (f32x4){0.f, 0.f, 0.f, 0.f};

  for (int i = 0; i < 4; ++i) {
    const unsigned short* gA = xreg + ((size_t)i * B_ + mt * 128) * KP + srcOff;
    const unsigned short* gB = w1g + ((size_t)i * H_ + h0) * KP + srcOff;
    f32x4 acc[4][2];
#pragma unroll
    for (int fm = 0; fm < 4; ++fm)
#pragma unroll
      for (int fn = 0; fn < 2; ++fn) acc[fm][fn] = (f32x4){0.f, 0.f, 0.f, 0.f};
    for (int kt = 0; kt < KP; kt += 32) {
      gload_lds16(gA + kt,            ldsTA);
      gload_lds16(gA + kt + 64 * KP,  ldsTA + 4096);
      gload_lds16(gB + kt,            ldsTB);
      __syncthreads();
      short8 af[4], bfr[2];
#pragma unroll
      for (int f = 0; f < 4; ++f) af[f] = *(const short8*)(lds + arow + f * 1024);
#pragma unroll
      for (int f = 0; f < 2; ++f) bfr[f] = *(const short8*)(lds + brow + f * 1024);
#pragma unroll
      for (int fm = 0; fm < 4; ++fm)
#pragma unroll
        for (int fn = 0; fn < 2; ++fn)
          acc[fm][fn] = __builtin_amdgcn_mfma_f32_16x16x32_bf16(af[fm], bfr[fn], acc[fm][fn], 0, 0, 0);
      __syncthreads();
    }
    // gelu + weighted fold into out[k] (register-only)
#pragma unroll
    for (int fm = 0; fm < 4; ++fm)
#pragma unroll
      for (int r = 0; r < 4; ++r) {
        const int m = mbase + 16 * fm + r;
        const float4 w4 = *(const float4*)(wts + (size_t)m * 64 + i * 16 + j * 4);
#pragma unroll
        for (int fn = 0; fn < 2; ++fn) {
          float v = acc[fm][fn][r] + (fn ? bias1 : bias0);
          float g = gelu_exact(v);
          out[0][fm][fn][r] += g * w4.x;
          out[1][fm][fn][r] += g * w4.y;
          out[2][fm][fn][r] += g * w4.z;
          out[3][fm][fn][r] += g * w4.w;
        }
      }
  }
  // epilogue: G[k][m][n] bf16
#pragma unroll
  for (int k = 0; k < 4; ++k) {
    unsigned short* Gk = G + (size_t)k * B_ * H_;
#pragma unroll
    for (int fm = 0; fm < 4; ++fm)
#pragma unroll
      for (int fn = 0; fn < 2; ++fn) {
        const int n = h0 + wc + 16 * fn + lr;
#pragma unroll
        for (int r = 0; r < 4; ++r) {
          const int m = mbase + 16 * fm + r;
          Gk[(size_t)m * H_ + n] = f2bf(out[k][fm][fn][r]);
        }
      }
  }
}

// C = A(128xK) * B(128xK)^T, both K-major bf16, K%32==0. T2-swizzled staging.
__device__ inline void gemm128_bt(const unsigned short* __restrict__ A,
                                  const unsigned short* __restrict__ Bm,
                                  int K, unsigned short* smem, f32x4 acc[4][4]) {
  const int t = threadIdx.x;
  const int w = t >> 6, l = t & 63;
  const int wr = (w >> 1) * 64, wc = (w & 1) * 64;
  const int lr = l & 15;
  const int swr = (lr >> 1) & 3;
  const int s_orig = (t & 3) ^ ((t >> 3) & 3);
  const size_t srcOff = (size_t)(t >> 2) * K + s_orig * 8;
  const unsigned short* gA = A + srcOff;
  const unsigned short* gB = Bm + srcOff;
  char* lds = (char*)smem;
  char* ldsT = lds + t * 16;
  const int arow = (wr + lr) * 64 + (((l >> 4) ^ swr) * 16);
  const int brow = 8192 + (wc + lr) * 64 + (((l >> 4) ^ swr) * 16);
  const size_t halfA = (size_t)64 * K;
  for (int kt = 0; kt < K; kt += 32) {
    gload_lds16(gA + kt,         ldsT);
    gload_lds16(gA + kt + halfA, ldsT + 4096);
    gload_lds16(gB + kt,         ldsT + 8192);
    gload_lds16(gB + kt + halfA, ldsT + 12288);
    __syncthreads();
    short8 af[4], bfr[4];
#pragma unroll
    for (int f = 0; f < 4; ++f) {
      af[f]  = *(const short8*)(lds + arow + f * 1024);
      bfr[f] = *(const short8*)(lds + brow + f * 1024);
    }
#pragma unroll
    for (int fm = 0; fm < 4; ++fm)
#pragma unroll
      for (int fn = 0; fn < 4; ++fn)
        acc[fm][fn] = __builtin_amdgcn_mfma_f32_16x16x32_bf16(af[fm], bfr[fn], acc[fm][fn], 0, 0, 0);
    __syncthreads();
  }
}

// ---- layer 2: out[b][k*256+o] = G_k @ W2_k^T + wsum[b][k]*b2 ----
__global__ __launch_bounds__(256) void k_l2(const unsigned short* __restrict__ G,
    const unsigned short* __restrict__ w2b, const float* __restrict__ b2,
    const float* __restrict__ wsum, float* __restrict__ out) {
  __shared__ __align__(128) unsigned short smem[8192];
  const int mt = blockIdx.x, nt = blockIdx.y, k = blockIdx.z;
  const unsigned short* A  = G + ((size_t)k * B_ + mt * 128) * H_;
  const unsigned short* Bm = w2b + ((size_t)(k * 256 + nt * 128)) * H_;
  f32x4 acc[4][4];
#pragma unroll
  for (int a = 0; a < 4; ++a)
#pragma unroll
    for (int b = 0; b < 4; ++b) acc[a][b] = (f32x4){0.f, 0.f, 0.f, 0.f};
  gemm128_bt(A, Bm, H_, smem, acc);
  const int t = threadIdx.x, w = t >> 6, l = t & 63;
  const int rbase = mt * 128 + (w >> 1) * 64 + (l >> 4) * 4;
  const int cb = nt * 128 + (w & 1) * 64 + (l & 15);
#pragma unroll
  for (int fn = 0; fn < 4; ++fn) {
    const int ncol = k * 256 + cb + fn * 16;
    const float bias = b2[ncol];
#pragma unroll
    for (int fm = 0; fm < 4; ++fm)
#pragma unroll
      for (int r = 0; r < 4; ++r) {
        const int m = rbase + fm * 16 + r;
        out[(size_t)m * O_ + ncol] = acc[fm][fn][r] + wsum[m * 4 + k] * bias;
      }
  }
}

extern "C" void kernel_launch(void* const* d_in, const int* in_sizes, int n_in,
                              void* d_out, int out_size, void* d_ws, size_t ws_size,
                              hipStream_t stream) {
  const float* x   = (const float*)d_in[0];
  const float* W1  = (const float*)d_in[1];
  const float* b1  = (const float*)d_in[2];
  const float* W2  = (const float*)d_in[3];
  const float* b2  = (const float*)d_in[4];
  const float* Wr1 = (const float*)d_in[5];
  const float* br1 = (const float*)d_in[6];
  const float* Wr2 = (const float*)d_in[7];
  const float* br2 = (const float*)d_in[8];
  const int*   ig  = (const int*)d_in[9];
  float* out = (float*)d_out;
  char* ws = (char*)d_ws;
  unsigned short* xreg = (unsigned short*)(ws);              // 14,680,064 B
  unsigned short* w1g  = (unsigned short*)(ws + 14680064);   //  3,670,016 B
  unsigned short* w2b  = (unsigned short*)(ws + 18350080);   //  4,194,304 B
  float*          wts  = (float*)(ws + 22544384);            //  2,097,152 B
  float*          wsum = (float*)(ws + 24641536);            //    131,072 B
  unsigned short* G    = (unsigned short*)(ws + 24772608);   // 134,217,728 B
  float*          hr   = (float*)(ws + 24772608);            // 4MB, aliases G (dead before l1c)

  k_prep<<<dim3(2048), dim3(256), 0, stream>>>(x, W1, W2, ig, xreg, w1g, w2b);
  k_r1<<<dim3(B_ / 64, RH_ / 64), dim3(256), 0, stream>>>(x, Wr1, br1, hr);
  k_r2<<<dim3(B_ / R2S), dim3(256), 0, stream>>>(hr, Wr2, br2, wts, wsum);
  k_l1c<<<dim3(B_ / 128, H_ / 64), dim3(256), 0, stream>>>(xreg, w1g, b1, wts, G);
  k_l2<<<dim3(B_ / 128, 2, 4), dim3(256), 0, stream>>>(G, w2b, b2, wsum, out);
}

// Round 4
// 260.941 us; speedup vs baseline: 1.1308x; 1.1308x over previous
//
#include <hip/hip_runtime.h>
#include <hip/hip_bf16.h>
#include <hip/hip_fp16.h>

#define B_  8192
#define D_  784
#define H_  2048
#define O_  1024
#define RH_ 128
#define P_  64
#define KP  224   // 196 padded to 7*32

typedef __attribute__((ext_vector_type(8))) short short8;
typedef __attribute__((ext_vector_type(4))) float f32x4;

__device__ inline float bf2f(unsigned short u) {
  union { unsigned int i; float f; } v; v.i = ((unsigned int)u) << 16; return v.f;
}
__device__ inline unsigned short f2bf(float f) {
  __hip_bfloat16 h = __float2bfloat16(f);
  return *reinterpret_cast<unsigned short*>(&h);
}
__device__ inline unsigned short f2h(float f) {
  __half h = __float2half(f);
  return *reinterpret_cast<unsigned short*>(&h);
}
__device__ inline float h2f(unsigned short u) {
  __half h = *reinterpret_cast<__half*>(&u);
  return __half2float(h);
}
// Abramowitz-Stegun 7.1.26, max abs err ~1.5e-7
__device__ inline float erf_fast(float x) {
  float ax = fabsf(x);
  float t = 1.0f / (1.0f + 0.3275911f * ax);
  float p = ((((1.061405429f * t - 1.453152027f) * t + 1.421413741f) * t
              - 0.284496736f) * t + 0.254829592f) * t;
  float y = 1.0f - p * __expf(-ax * ax);
  return x < 0.f ? -y : y;
}
__device__ inline float gelu_exact(float v) {
  return 0.5f * v * (1.0f + erf_fast(v * 0.70710678118654752f));
}

__device__ inline void gload_lds16(const void* g, void* l) {
  __builtin_amdgcn_global_load_lds((const __attribute__((address_space(1))) void*)g,
                                   (__attribute__((address_space(3))) void*)l, 16, 0, 0);
}

// C = A(128xK) * B(128xK)^T, both K-major bf16, K%32==0. T2-swizzled staging
// (conflict-free, verified R3: SQ_LDS_BANK_CONFLICT == 0).
__device__ inline void gemm128_bt(const unsigned short* __restrict__ A,
                                  const unsigned short* __restrict__ Bm,
                                  int K, unsigned short* smem, f32x4 acc[4][4]) {
  const int t = threadIdx.x;
  const int w = t >> 6, l = t & 63;
  const int wr = (w >> 1) * 64, wc = (w & 1) * 64;
  const int lr = l & 15;
  const int swr = (lr >> 1) & 3;
  const int s_orig = (t & 3) ^ ((t >> 3) & 3);
  const size_t srcOff = (size_t)(t >> 2) * K + s_orig * 8;
  const unsigned short* gA = A + srcOff;
  const unsigned short* gB = Bm + srcOff;
  char* lds = (char*)smem;
  char* ldsT = lds + t * 16;
  const int arow = (wr + lr) * 64 + (((l >> 4) ^ swr) * 16);
  const int brow = 8192 + (wc + lr) * 64 + (((l >> 4) ^ swr) * 16);
  const size_t halfA = (size_t)64 * K;
  for (int kt = 0; kt < K; kt += 32) {
    gload_lds16(gA + kt,         ldsT);
    gload_lds16(gA + kt + halfA, ldsT + 4096);
    gload_lds16(gB + kt,         ldsT + 8192);
    gload_lds16(gB + kt + halfA, ldsT + 12288);
    __syncthreads();
    short8 af[4], bfr[4];
#pragma unroll
    for (int f = 0; f < 4; ++f) {
      af[f]  = *(const short8*)(lds + arow + f * 1024);
      bfr[f] = *(const short8*)(lds + brow + f * 1024);
    }
#pragma unroll
    for (int fm = 0; fm < 4; ++fm)
#pragma unroll
      for (int fn = 0; fn < 4; ++fn)
        acc[fm][fn] = __builtin_amdgcn_mfma_f32_16x16x32_bf16(af[fm], bfr[fn], acc[fm][fn], 0, 0, 0);
    __syncthreads();
  }
}

// ---- prep: gather/pad/convert x_reg, W1g; convert W2 to bf16 ----
__global__ void k_prep(const float* __restrict__ x, const float* __restrict__ W1,
                       const float* __restrict__ W2, const int* __restrict__ ig,
                       unsigned short* __restrict__ xreg, unsigned short* __restrict__ w1g,
                       unsigned short* __restrict__ w2b) {
  const size_t N1 = (size_t)4 * B_ * KP;
  const size_t N2 = (size_t)4 * H_ * KP;
  const size_t N3 = (size_t)O_ * H_;
  const size_t TOT = N1 + N2 + N3;
  for (size_t idx = (size_t)blockIdx.x * blockDim.x + threadIdx.x; idx < TOT;
       idx += (size_t)gridDim.x * blockDim.x) {
    if (idx < N1) {
      int n = (int)(idx % KP); size_t r = idx / KP;
      int b = (int)(r % B_); int i = (int)(r / B_);
      float v = (n < 196) ? x[(size_t)b * D_ + ig[i * 196 + n]] : 0.f;
      xreg[idx] = f2bf(v);
    } else if (idx < N1 + N2) {
      size_t q = idx - N1;
      int n = (int)(q % KP); size_t r = q / KP;
      int h = (int)(r % H_); int i = (int)(r / H_);
      float v = (n < 196) ? W1[(size_t)h * D_ + ig[i * 196 + n]] : 0.f;
      w1g[q] = f2bf(v);
    } else {
      size_t q = idx - N1 - N2;
      w2b[q] = f2bf(W2[q]);
    }
  }
}

// ---- router stage 1: h_r = relu(x @ Wr1^T + br1), fp32 register-blocked GEMM ----
__global__ __launch_bounds__(256) void k_r1(const float* __restrict__ x,
    const float* __restrict__ Wr1, const float* __restrict__ br1,
    float* __restrict__ hr) {
  __shared__ float As[64][33];
  __shared__ float Bs[64][33];
  const int b0 = blockIdx.x * 64;
  const int h0 = blockIdx.y * 64;
  const int t = threadIdx.x;
  const int srow = t >> 2;
  const int scol = (t & 3) * 8;
  const int ty = t >> 4, tx = t & 15;
  float acc[4][4];
#pragma unroll
  for (int i = 0; i < 4; ++i)
#pragma unroll
    for (int j = 0; j < 4; ++j) acc[i][j] = 0.f;
  const float* gA = x   + (size_t)(b0 + srow) * D_;
  const float* gB = Wr1 + (size_t)(h0 + srow) * D_;
  for (int k0 = 0; k0 < D_; k0 += 32) {
    float4 a0 = (k0 + scol     < D_) ? *(const float4*)(gA + k0 + scol)     : float4{0,0,0,0};
    float4 a1 = (k0 + scol + 4 < D_) ? *(const float4*)(gA + k0 + scol + 4) : float4{0,0,0,0};
    float4 w0 = (k0 + scol     < D_) ? *(const float4*)(gB + k0 + scol)     : float4{0,0,0,0};
    float4 w1 = (k0 + scol + 4 < D_) ? *(const float4*)(gB + k0 + scol + 4) : float4{0,0,0,0};
    __syncthreads();
    *(float4*)&As[srow][scol]     = a0;
    *(float4*)&As[srow][scol + 4] = a1;
    *(float4*)&Bs[srow][scol]     = w0;
    *(float4*)&Bs[srow][scol + 4] = w1;
    __syncthreads();
#pragma unroll
    for (int kk = 0; kk < 8; ++kk) {
      float4 a4[4], b4[4];
#pragma unroll
      for (int i = 0; i < 4; ++i) a4[i] = *(const float4*)&As[ty * 4 + i][kk * 4];
#pragma unroll
      for (int j = 0; j < 4; ++j) b4[j] = *(const float4*)&Bs[tx * 4 + j][kk * 4];
#pragma unroll
      for (int i = 0; i < 4; ++i)
#pragma unroll
        for (int j = 0; j < 4; ++j)
          acc[i][j] += a4[i].x * b4[j].x + a4[i].y * b4[j].y +
                       a4[i].z * b4[j].z + a4[i].w * b4[j].w;
    }
  }
#pragma unroll
  for (int j = 0; j < 4; ++j) {
    const int h = h0 + tx * 4 + j;
    const float bias = br1[h];
#pragma unroll
    for (int i = 0; i < 4; ++i)
      hr[(size_t)(b0 + ty * 4 + i) * RH_ + h] = fmaxf(acc[i][j] + bias, 0.f);
  }
}

// ---- router stage 2: scores -> softmax -> top-8 -> weights. One wave per sample. ----
#define R2S 32
__global__ __launch_bounds__(256) void k_r2(const float* __restrict__ hr,
    const float* __restrict__ Wr2, const float* __restrict__ br2,
    float* __restrict__ wts, float* __restrict__ wsum) {
  __shared__ float Ws[64][130];
  __shared__ float hs[R2S][128];
  const int s0 = blockIdx.x * R2S;
  const int t = threadIdx.x;
  for (int idx = t; idx < 2048; idx += 256) {
    int r = idx >> 5, c = (idx & 31) * 4;
    *(float4*)&Ws[r][c] = *(const float4*)(Wr2 + (size_t)r * RH_ + c);
  }
  for (int idx = t; idx < R2S * 32; idx += 256) {
    int r = idx >> 5, c = (idx & 31) * 4;
    *(float4*)&hs[r][c] = *(const float4*)(hr + (size_t)(s0 + r) * RH_ + c);
  }
  __syncthreads();
  const int w = t >> 6, p = t & 63;
  const float wb2 = br2[p];
  for (int si = 0; si < R2S / 4; ++si) {
    const int sl = w * (R2S / 4) + si;
    float sc = wb2;
#pragma unroll
    for (int kk = 0; kk < 32; ++kk) {
      float4 h4 = *(const float4*)&hs[sl][kk * 4];
      float4 w4 = *(const float4*)&Ws[p][kk * 4];
      sc += h4.x * w4.x + h4.y * w4.y + h4.z * w4.z + h4.w * w4.w;
    }
    float m = sc;
#pragma unroll
    for (int o = 32; o; o >>= 1) m = fmaxf(m, __shfl_xor(m, o));
    float e = __expf(sc - m);
    float Z = e;
#pragma unroll
    for (int o = 32; o; o >>= 1) Z += __shfl_xor(Z, o);
    bool sel = false;
    float ssum = 0.f;
    for (int it = 0; it < 8; ++it) {
      float v = sel ? -1.f : e;
      float vm = v;
#pragma unroll
      for (int o = 32; o; o >>= 1) vm = fmaxf(vm, __shfl_xor(vm, o));
      unsigned long long mask = __ballot(!sel && v == vm);
      int first = __ffsll((long long)mask) - 1;
      if (p == first) sel = true;
      ssum += vm;
    }
    const float dn = 1.0f / (ssum + 1e-8f * Z);
    const float wv = sel ? e * dn : 0.f;
    wts[(size_t)(s0 + sl) * 64 + p] = wv;
    float part = wv;
#pragma unroll
    for (int o = 4; o < 64; o <<= 1) part += __shfl_xor(part, o);
    if (p < 4) wsum[(size_t)(s0 + sl) * 4 + p] = part;
  }
}

// ---- layer 1: hid16[i][b][n] = fp16(xreg_i @ w1g_i^T + b1)  (pre-activation) ----
__global__ __launch_bounds__(256) void k_l1(const unsigned short* __restrict__ xreg,
    const unsigned short* __restrict__ w1g, const float* __restrict__ b1,
    unsigned short* __restrict__ hid16) {
  __shared__ __align__(128) unsigned short smem[8192];
  const int mt = blockIdx.x, nt = blockIdx.y, iq = blockIdx.z;
  const unsigned short* A  = xreg + ((size_t)iq * B_ + mt * 128) * KP;
  const unsigned short* Bm = w1g + ((size_t)iq * H_ + nt * 128) * KP;
  f32x4 acc[4][4];
#pragma unroll
  for (int a = 0; a < 4; ++a)
#pragma unroll
    for (int b = 0; b < 4; ++b) acc[a][b] = (f32x4){0.f, 0.f, 0.f, 0.f};
  gemm128_bt(A, Bm, KP, smem, acc);
  const int t = threadIdx.x, w = t >> 6, l = t & 63;
  const int rbase = mt * 128 + (w >> 1) * 64 + (l >> 4) * 4;
  const int cbase = nt * 128 + (w & 1) * 64 + (l & 15);
#pragma unroll
  for (int fn = 0; fn < 4; ++fn) {
    const int n = cbase + fn * 16;
    const float bias = b1[n];
#pragma unroll
    for (int fm = 0; fm < 4; ++fm)
#pragma unroll
      for (int r = 0; r < 4; ++r) {
        const int m = rbase + fm * 16 + r;
        hid16[((size_t)iq * B_ + m) * H_ + n] = f2h(acc[fm][fn][r] + bias);
      }
  }
}

// ---- combine (in-place, fp16 pre-act -> gelu -> weighted fold -> bf16 G) ----
__global__ __launch_bounds__(256) void k_combine(unsigned short* __restrict__ hid,
                                                 const float* __restrict__ wts) {
  const int b = blockIdx.x;
  const int n = threadIdx.x * 8;
  const int j = n >> 9;
  const float* wb = wts + (size_t)b * 64;
  float g[4][8];
#pragma unroll
  for (int i = 0; i < 4; ++i) {
    short8 raw = *(const short8*)(hid + ((size_t)i * B_ + b) * H_ + n);
#pragma unroll
    for (int e = 0; e < 8; ++e) g[i][e] = gelu_exact(h2f((unsigned short)raw[e]));
  }
  short8 outv[4];
#pragma unroll
  for (int k = 0; k < 4; ++k) {
    const float w0 = wb[0 + j * 4 + k], w1 = wb[16 + j * 4 + k];
    const float w2 = wb[32 + j * 4 + k], w3 = wb[48 + j * 4 + k];
#pragma unroll
    for (int e = 0; e < 8; ++e) {
      float sv = g[0][e] * w0 + g[1][e] * w1 + g[2][e] * w2 + g[3][e] * w3;
      outv[k][e] = (short)f2bf(sv);
    }
  }
#pragma unroll
  for (int k = 0; k < 4; ++k)
    *(short8*)(hid + ((size_t)k * B_ + b) * H_ + n) = outv[k];
}

// ---- layer 2: out[b][k*256+o] = G_k @ W2_k^T + wsum[b][k]*b2 ----
__global__ __launch_bounds__(256) void k_l2(const unsigned short* __restrict__ G,
    const unsigned short* __restrict__ w2b, const float* __restrict__ b2,
    const float* __restrict__ wsum, float* __restrict__ out) {
  __shared__ __align__(128) unsigned short smem[8192];
  const int mt = blockIdx.x, nt = blockIdx.y, k = blockIdx.z;
  const unsigned short* A  = G + ((size_t)k * B_ + mt * 128) * H_;
  const unsigned short* Bm = w2b + ((size_t)(k * 256 + nt * 128)) * H_;
  f32x4 acc[4][4];
#pragma unroll
  for (int a = 0; a < 4; ++a)
#pragma unroll
    for (int b = 0; b < 4; ++b) acc[a][b] = (f32x4){0.f, 0.f, 0.f, 0.f};
  gemm128_bt(A, Bm, H_, smem, acc);
  const int t = threadIdx.x, w = t >> 6, l = t & 63;
  const int rbase = mt * 128 + (w >> 1) * 64 + (l >> 4) * 4;
  const int cb = nt * 128 + (w & 1) * 64 + (l & 15);
#pragma unroll
  for (int fn = 0; fn < 4; ++fn) {
    const int ncol = k * 256 + cb + fn * 16;
    const float bias = b2[ncol];
#pragma unroll
    for (int fm = 0; fm < 4; ++fm)
#pragma unroll
      for (int r = 0; r < 4; ++r) {
        const int m = rbase + fm * 16 + r;
        out[(size_t)m * O_ + ncol] = acc[fm][fn][r] + wsum[m * 4 + k] * bias;
      }
  }
}

extern "C" void kernel_launch(void* const* d_in, const int* in_sizes, int n_in,
                              void* d_out, int out_size, void* d_ws, size_t ws_size,
                              hipStream_t stream) {
  const float* x   = (const float*)d_in[0];
  const float* W1  = (const float*)d_in[1];
  const float* b1  = (const float*)d_in[2];
  const float* W2  = (const float*)d_in[3];
  const float* b2  = (const float*)d_in[4];
  const float* Wr1 = (const float*)d_in[5];
  const float* br1 = (const float*)d_in[6];
  const float* Wr2 = (const float*)d_in[7];
  const float* br2 = (const float*)d_in[8];
  const int*   ig  = (const int*)d_in[9];
  float* out = (float*)d_out;
  char* ws = (char*)d_ws;
  unsigned short* xreg = (unsigned short*)(ws);              // 14,680,064 B
  unsigned short* w1g  = (unsigned short*)(ws + 14680064);   //  3,670,016 B
  unsigned short* w2b  = (unsigned short*)(ws + 18350080);   //  4,194,304 B
  float*          wts  = (float*)(ws + 22544384);            //  2,097,152 B
  float*          wsum = (float*)(ws + 24641536);            //    131,072 B
  unsigned short* hid  = (unsigned short*)(ws + 24772608);   // 134,217,728 B (fp16 pre-act, then bf16 G in-place)
  float*          hr   = (float*)(ws + 24772608);            // 4MB, aliases hid (dead before l1)

  k_prep<<<dim3(2048), dim3(256), 0, stream>>>(x, W1, W2, ig, xreg, w1g, w2b);
  k_r1<<<dim3(B_ / 64, RH_ / 64), dim3(256), 0, stream>>>(x, Wr1, br1, hr);
  k_r2<<<dim3(B_ / R2S), dim3(256), 0, stream>>>(hr, Wr2, br2, wts, wsum);
  k_l1<<<dim3(B_ / 128, H_ / 128, 4), dim3(256), 0, stream>>>(xreg, w1g, b1, hid);
  k_combine<<<dim3(B_), dim3(256), 0, stream>>>(hid, wts);
  k_l2<<<dim3(B_ / 128, 2, 4), dim3(256), 0, stream>>>(hid, w2b, b2, wsum, out);
}

// Round 5
// 253.502 us; speedup vs baseline: 1.1640x; 1.0293x over previous
//
#include <hip/hip_runtime.h>
#include <hip/hip_bf16.h>
#include <hip/hip_fp16.h>

#define B_  8192
#define D_  784
#define H_  2048
#define O_  1024
#define RH_ 128
#define P_  64
#define KP  224   // 196 padded to 7*32
#define KC  196   // split-K chunk for router stage 1

typedef __attribute__((ext_vector_type(8))) short short8;
typedef __attribute__((ext_vector_type(4))) float f32x4;

__device__ inline float bf2f(unsigned short u) {
  union { unsigned int i; float f; } v; v.i = ((unsigned int)u) << 16; return v.f;
}
__device__ inline unsigned short f2bf(float f) {
  __hip_bfloat16 h = __float2bfloat16(f);
  return *reinterpret_cast<unsigned short*>(&h);
}
__device__ inline unsigned short f2h(float f) {
  __half h = __float2half(f);
  return *reinterpret_cast<unsigned short*>(&h);
}
__device__ inline float h2f(unsigned short u) {
  __half h = *reinterpret_cast<__half*>(&u);
  return __half2float(h);
}
// Abramowitz-Stegun 7.1.26, max abs err ~1.5e-7
__device__ inline float erf_fast(float x) {
  float ax = fabsf(x);
  float t = 1.0f / (1.0f + 0.3275911f * ax);
  float p = ((((1.061405429f * t - 1.453152027f) * t + 1.421413741f) * t
              - 0.284496736f) * t + 0.254829592f) * t;
  float y = 1.0f - p * __expf(-ax * ax);
  return x < 0.f ? -y : y;
}
__device__ inline float gelu_exact(float v) {
  return 0.5f * v * (1.0f + erf_fast(v * 0.70710678118654752f));
}

__device__ inline void gload_lds16(const void* g, void* l) {
  __builtin_amdgcn_global_load_lds((const __attribute__((address_space(1))) void*)g,
                                   (__attribute__((address_space(3))) void*)l, 16, 0, 0);
}

// C = A(128xK) * B(128xK)^T, both K-major bf16, K%32==0. T2-swizzled staging
// (conflict-free, verified R3: SQ_LDS_BANK_CONFLICT == 0).
__device__ inline void gemm128_bt(const unsigned short* __restrict__ A,
                                  const unsigned short* __restrict__ Bm,
                                  int K, unsigned short* smem, f32x4 acc[4][4]) {
  const int t = threadIdx.x;
  const int w = t >> 6, l = t & 63;
  const int wr = (w >> 1) * 64, wc = (w & 1) * 64;
  const int lr = l & 15;
  const int swr = (lr >> 1) & 3;
  const int s_orig = (t & 3) ^ ((t >> 3) & 3);
  const size_t srcOff = (size_t)(t >> 2) * K + s_orig * 8;
  const unsigned short* gA = A + srcOff;
  const unsigned short* gB = Bm + srcOff;
  char* lds = (char*)smem;
  char* ldsT = lds + t * 16;
  const int arow = (wr + lr) * 64 + (((l >> 4) ^ swr) * 16);
  const int brow = 8192 + (wc + lr) * 64 + (((l >> 4) ^ swr) * 16);
  const size_t halfA = (size_t)64 * K;
  for (int kt = 0; kt < K; kt += 32) {
    gload_lds16(gA + kt,         ldsT);
    gload_lds16(gA + kt + halfA, ldsT + 4096);
    gload_lds16(gB + kt,         ldsT + 8192);
    gload_lds16(gB + kt + halfA, ldsT + 12288);
    __syncthreads();
    short8 af[4], bfr[4];
#pragma unroll
    for (int f = 0; f < 4; ++f) {
      af[f]  = *(const short8*)(lds + arow + f * 1024);
      bfr[f] = *(const short8*)(lds + brow + f * 1024);
    }
#pragma unroll
    for (int fm = 0; fm < 4; ++fm)
#pragma unroll
      for (int fn = 0; fn < 4; ++fn)
        acc[fm][fn] = __builtin_amdgcn_mfma_f32_16x16x32_bf16(af[fm], bfr[fn], acc[fm][fn], 0, 0, 0);
    __syncthreads();
  }
}

// ---- prep: gather/pad/convert x_reg, W1g; convert W2 to bf16 ----
__global__ void k_prep(const float* __restrict__ x, const float* __restrict__ W1,
                       const float* __restrict__ W2, const int* __restrict__ ig,
                       unsigned short* __restrict__ xreg, unsigned short* __restrict__ w1g,
                       unsigned short* __restrict__ w2b) {
  const size_t N1 = (size_t)4 * B_ * KP;
  const size_t N2 = (size_t)4 * H_ * KP;
  const size_t N3 = (size_t)O_ * H_;
  const size_t TOT = N1 + N2 + N3;
  for (size_t idx = (size_t)blockIdx.x * blockDim.x + threadIdx.x; idx < TOT;
       idx += (size_t)gridDim.x * blockDim.x) {
    if (idx < N1) {
      int n = (int)(idx % KP); size_t r = idx / KP;
      int b = (int)(r % B_); int i = (int)(r / B_);
      float v = (n < 196) ? x[(size_t)b * D_ + ig[i * 196 + n]] : 0.f;
      xreg[idx] = f2bf(v);
    } else if (idx < N1 + N2) {
      size_t q = idx - N1;
      int n = (int)(q % KP); size_t r = q / KP;
      int h = (int)(r % H_); int i = (int)(r / H_);
      float v = (n < 196) ? W1[(size_t)h * D_ + ig[i * 196 + n]] : 0.f;
      w1g[q] = f2bf(v);
    } else {
      size_t q = idx - N1 - N2;
      w2b[q] = f2bf(W2[q]);
    }
  }
}

// ---- router stage 1, split-K: hrp[z][b][h] = partial (x @ Wr1^T) over K-chunk z ----
// grid (B/64, RH/64, 4); deterministic (no atomics); bias folded into z==0.
__global__ __launch_bounds__(256) void k_r1s(const float* __restrict__ x,
    const float* __restrict__ Wr1, const float* __restrict__ br1,
    float* __restrict__ hrp) {
  __shared__ float As[64][33];
  __shared__ float Bs[64][33];
  const int b0 = blockIdx.x * 64;
  const int h0 = blockIdx.y * 64;
  const int kb = blockIdx.z * KC;
  const int kend = kb + KC;
  const int t = threadIdx.x;
  const int srow = t >> 2;
  const int scol = (t & 3) * 8;
  const int ty = t >> 4, tx = t & 15;
  float acc[4][4];
#pragma unroll
  for (int i = 0; i < 4; ++i)
#pragma unroll
    for (int j = 0; j < 4; ++j) acc[i][j] = 0.f;
  const float* gA = x   + (size_t)(b0 + srow) * D_;
  const float* gB = Wr1 + (size_t)(h0 + srow) * D_;
  for (int k0 = kb; k0 < kend; k0 += 32) {
    float4 a0 = (k0 + scol + 4  <= kend) ? *(const float4*)(gA + k0 + scol)     : float4{0,0,0,0};
    float4 a1 = (k0 + scol + 8  <= kend) ? *(const float4*)(gA + k0 + scol + 4) : float4{0,0,0,0};
    float4 w0 = (k0 + scol + 4  <= kend) ? *(const float4*)(gB + k0 + scol)     : float4{0,0,0,0};
    float4 w1 = (k0 + scol + 8  <= kend) ? *(const float4*)(gB + k0 + scol + 4) : float4{0,0,0,0};
    __syncthreads();
    *(float4*)&As[srow][scol]     = a0;
    *(float4*)&As[srow][scol + 4] = a1;
    *(float4*)&Bs[srow][scol]     = w0;
    *(float4*)&Bs[srow][scol + 4] = w1;
    __syncthreads();
#pragma unroll
    for (int kk = 0; kk < 8; ++kk) {
      float4 a4[4], b4[4];
#pragma unroll
      for (int i = 0; i < 4; ++i) a4[i] = *(const float4*)&As[ty * 4 + i][kk * 4];
#pragma unroll
      for (int j = 0; j < 4; ++j) b4[j] = *(const float4*)&Bs[tx * 4 + j][kk * 4];
#pragma unroll
      for (int i = 0; i < 4; ++i)
#pragma unroll
        for (int j = 0; j < 4; ++j)
          acc[i][j] += a4[i].x * b4[j].x + a4[i].y * b4[j].y +
                       a4[i].z * b4[j].z + a4[i].w * b4[j].w;
    }
  }
  float* hz = hrp + (size_t)blockIdx.z * B_ * RH_;
#pragma unroll
  for (int j = 0; j < 4; ++j) {
    const int h = h0 + tx * 4 + j;
    const float bias = (blockIdx.z == 0) ? br1[h] : 0.f;
#pragma unroll
    for (int i = 0; i < 4; ++i)
      hz[(size_t)(b0 + ty * 4 + i) * RH_ + h] = acc[i][j] + bias;
  }
}

// ---- router stage 2: reduce partials + relu, scores -> softmax -> top-8 -> weights ----
#define R2S 32
__global__ __launch_bounds__(256) void k_r2(const float* __restrict__ hrp,
    const float* __restrict__ Wr2, const float* __restrict__ br2,
    float* __restrict__ wts, float* __restrict__ wsum) {
  __shared__ float Ws[64][130];
  __shared__ float hs[R2S][128];
  const int s0 = blockIdx.x * R2S;
  const int t = threadIdx.x;
  for (int idx = t; idx < 2048; idx += 256) {
    int r = idx >> 5, c = (idx & 31) * 4;
    *(float4*)&Ws[r][c] = *(const float4*)(Wr2 + (size_t)r * RH_ + c);
  }
  for (int idx = t; idx < R2S * 32; idx += 256) {
    int r = idx >> 5, c = (idx & 31) * 4;
    const size_t off = (size_t)(s0 + r) * RH_ + c;
    float4 p0 = *(const float4*)(hrp + off);
    float4 p1 = *(const float4*)(hrp + (size_t)1 * B_ * RH_ + off);
    float4 p2 = *(const float4*)(hrp + (size_t)2 * B_ * RH_ + off);
    float4 p3 = *(const float4*)(hrp + (size_t)3 * B_ * RH_ + off);
    float4 s;
    s.x = fmaxf(p0.x + p1.x + p2.x + p3.x, 0.f);
    s.y = fmaxf(p0.y + p1.y + p2.y + p3.y, 0.f);
    s.z = fmaxf(p0.z + p1.z + p2.z + p3.z, 0.f);
    s.w = fmaxf(p0.w + p1.w + p2.w + p3.w, 0.f);
    *(float4*)&hs[r][c] = s;
  }
  __syncthreads();
  const int w = t >> 6, p = t & 63;
  const float wb2 = br2[p];
  for (int si = 0; si < R2S / 4; ++si) {
    const int sl = w * (R2S / 4) + si;
    float sc = wb2;
#pragma unroll
    for (int kk = 0; kk < 32; ++kk) {
      float4 h4 = *(const float4*)&hs[sl][kk * 4];
      float4 w4 = *(const float4*)&Ws[p][kk * 4];
      sc += h4.x * w4.x + h4.y * w4.y + h4.z * w4.z + h4.w * w4.w;
    }
    float m = sc;
#pragma unroll
    for (int o = 32; o; o >>= 1) m = fmaxf(m, __shfl_xor(m, o));
    float e = __expf(sc - m);
    float Z = e;
#pragma unroll
    for (int o = 32; o; o >>= 1) Z += __shfl_xor(Z, o);
    bool sel = false;
    float ssum = 0.f;
    for (int it = 0; it < 8; ++it) {
      float v = sel ? -1.f : e;
      float vm = v;
#pragma unroll
      for (int o = 32; o; o >>= 1) vm = fmaxf(vm, __shfl_xor(vm, o));
      unsigned long long mask = __ballot(!sel && v == vm);
      int first = __ffsll((long long)mask) - 1;
      if (p == first) sel = true;
      ssum += vm;
    }
    const float dn = 1.0f / (ssum + 1e-8f * Z);
    const float wv = sel ? e * dn : 0.f;
    wts[(size_t)(s0 + sl) * 64 + p] = wv;
    float part = wv;
#pragma unroll
    for (int o = 4; o < 64; o <<= 1) part += __shfl_xor(part, o);
    if (p < 4) wsum[(size_t)(s0 + sl) * 4 + p] = part;
  }
}

// ---- layer 1: hid16[i][b][n] = fp16(xreg_i @ w1g_i^T + b1)  (pre-activation) ----
__global__ __launch_bounds__(256) void k_l1(const unsigned short* __restrict__ xreg,
    const unsigned short* __restrict__ w1g, const float* __restrict__ b1,
    unsigned short* __restrict__ hid16) {
  __shared__ __align__(128) unsigned short smem[8192];
  const int mt = blockIdx.x, nt = blockIdx.y, iq = blockIdx.z;
  const unsigned short* A  = xreg + ((size_t)iq * B_ + mt * 128) * KP;
  const unsigned short* Bm = w1g + ((size_t)iq * H_ + nt * 128) * KP;
  f32x4 acc[4][4];
#pragma unroll
  for (int a = 0; a < 4; ++a)
#pragma unroll
    for (int b = 0; b < 4; ++b) acc[a][b] = (f32x4){0.f, 0.f, 0.f, 0.f};
  gemm128_bt(A, Bm, KP, smem, acc);
  const int t = threadIdx.x, w = t >> 6, l = t & 63;
  const int rbase = mt * 128 + (w >> 1) * 64 + (l >> 4) * 4;
  const int cbase = nt * 128 + (w & 1) * 64 + (l & 15);
#pragma unroll
  for (int fn = 0; fn < 4; ++fn) {
    const int n = cbase + fn * 16;
    const float bias = b1[n];
#pragma unroll
    for (int fm = 0; fm < 4; ++fm)
#pragma unroll
      for (int r = 0; r < 4; ++r) {
        const int m = rbase + fm * 16 + r;
        hid16[((size_t)iq * B_ + m) * H_ + n] = f2h(acc[fm][fn][r] + bias);
      }
  }
}

// ---- combine (in-place, fp16 pre-act -> gelu -> weighted fold -> bf16 G) ----
__global__ __launch_bounds__(256) void k_combine(unsigned short* __restrict__ hid,
                                                 const float* __restrict__ wts) {
  const int b = blockIdx.x;
  const int n = threadIdx.x * 8;
  const int j = n >> 9;
  const float* wb = wts + (size_t)b * 64;
  float g[4][8];
#pragma unroll
  for (int i = 0; i < 4; ++i) {
    short8 raw = *(const short8*)(hid + ((size_t)i * B_ + b) * H_ + n);
#pragma unroll
    for (int e = 0; e < 8; ++e) g[i][e] = gelu_exact(h2f((unsigned short)raw[e]));
  }
  short8 outv[4];
#pragma unroll
  for (int k = 0; k < 4; ++k) {
    const float w0 = wb[0 + j * 4 + k], w1 = wb[16 + j * 4 + k];
    const float w2 = wb[32 + j * 4 + k], w3 = wb[48 + j * 4 + k];
#pragma unroll
    for (int e = 0; e < 8; ++e) {
      float sv = g[0][e] * w0 + g[1][e] * w1 + g[2][e] * w2 + g[3][e] * w3;
      outv[k][e] = (short)f2bf(sv);
    }
  }
#pragma unroll
  for (int k = 0; k < 4; ++k)
    *(short8*)(hid + ((size_t)k * B_ + b) * H_ + n) = outv[k];
}

// ---- layer 2: out[b][k*256+o] = G_k @ W2_k^T + wsum[b][k]*b2 ----
__global__ __launch_bounds__(256) void k_l2(const unsigned short* __restrict__ G,
    const unsigned short* __restrict__ w2b, const float* __restrict__ b2,
    const float* __restrict__ wsum, float* __restrict__ out) {
  __shared__ __align__(128) unsigned short smem[8192];
  const int mt = blockIdx.x, nt = blockIdx.y, k = blockIdx.z;
  const unsigned short* A  = G + ((size_t)k * B_ + mt * 128) * H_;
  const unsigned short* Bm = w2b + ((size_t)(k * 256 + nt * 128)) * H_;
  f32x4 acc[4][4];
#pragma unroll
  for (int a = 0; a < 4; ++a)
#pragma unroll
    for (int b = 0; b < 4; ++b) acc[a][b] = (f32x4){0.f, 0.f, 0.f, 0.f};
  gemm128_bt(A, Bm, H_, smem, acc);
  const int t = threadIdx.x, w = t >> 6, l = t & 63;
  const int rbase = mt * 128 + (w >> 1) * 64 + (l >> 4) * 4;
  const int cb = nt * 128 + (w & 1) * 64 + (l & 15);
#pragma unroll
  for (int fn = 0; fn < 4; ++fn) {
    const int ncol = k * 256 + cb + fn * 16;
    const float bias = b2[ncol];
#pragma unroll
    for (int fm = 0; fm < 4; ++fm)
#pragma unroll
      for (int r = 0; r < 4; ++r) {
        const int m = rbase + fm * 16 + r;
        out[(size_t)m * O_ + ncol] = acc[fm][fn][r] + wsum[m * 4 + k] * bias;
      }
  }
}

extern "C" void kernel_launch(void* const* d_in, const int* in_sizes, int n_in,
                              void* d_out, int out_size, void* d_ws, size_t ws_size,
                              hipStream_t stream) {
  const float* x   = (const float*)d_in[0];
  const float* W1  = (const float*)d_in[1];
  const float* b1  = (const float*)d_in[2];
  const float* W2  = (const float*)d_in[3];
  const float* b2  = (const float*)d_in[4];
  const float* Wr1 = (const float*)d_in[5];
  const float* br1 = (const float*)d_in[6];
  const float* Wr2 = (const float*)d_in[7];
  const float* br2 = (const float*)d_in[8];
  const int*   ig  = (const int*)d_in[9];
  float* out = (float*)d_out;
  char* ws = (char*)d_ws;
  unsigned short* xreg = (unsigned short*)(ws);              // 14,680,064 B
  unsigned short* w1g  = (unsigned short*)(ws + 14680064);   //  3,670,016 B
  unsigned short* w2b  = (unsigned short*)(ws + 18350080);   //  4,194,304 B
  float*          wts  = (float*)(ws + 22544384);            //  2,097,152 B
  float*          wsum = (float*)(ws + 24641536);            //    131,072 B
  unsigned short* hid  = (unsigned short*)(ws + 24772608);   // 134,217,728 B (fp16 pre-act, then bf16 G in-place)
  float*          hrp  = (float*)(ws + 24772608);            // 4 x 4MB split-K partials, alias hid (dead before l1)

  k_prep<<<dim3(2048), dim3(256), 0, stream>>>(x, W1, W2, ig, xreg, w1g, w2b);
  k_r1s<<<dim3(B_ / 64, RH_ / 64, 4), dim3(256), 0, stream>>>(x, Wr1, br1, hrp);
  k_r2<<<dim3(B_ / R2S), dim3(256), 0, stream>>>(hrp, Wr2, br2, wts, wsum);
  k_l1<<<dim3(B_ / 128, H_ / 128, 4), dim3(256), 0, stream>>>(xreg, w1g, b1, hid);
  k_combine<<<dim3(B_), dim3(256), 0, stream>>>(hid, wts);
  k_l2<<<dim3(B_ / 128, 2, 4), dim3(256), 0, stream>>>(hid, w2b, b2, wsum, out);
}